// Round 1
// baseline (540.779 us; speedup 1.0000x reference)
//
#include <hip/hip_runtime.h>

// MoE fused kernel, MI355X gfx950 — Round 4: occupancy unblock.
// Shapes: B=65536, D=512, C=101, E=8, H=256.
// out[b,c] = sum_{e,h} g[b,e]*relu(x@W1+b1)[b,e,h]*W2[e,h,c] + sum_e g[b,e]*b2[e,c]
// g = softmax(x@Wg+bg), gate logits folded into layer1 GEMM as cols 2048..2055.
//
// R4: R3 was latency-bound at 2 waves/SIMD (MfmaUtil 21%, VALU 17%, occ 23%):
// LDS 100KB -> 1 block/CU AND acc2[4][8]=128 regs -> ~240 unified regs/wave.
// Restructure layer2 from per-wave K-slice (128 acc regs + 8-way end reduction)
// to per-wave ct-ownership: wave w owns output cols [w*32,w*32+32) over FULL K,
// acc2[2][2]=16 regs, no reduction. h' handoff through shared hA (16KB) with
// 2 barriers/nt. Mtile 64->32, 256-thread blocks (4 waves): LDS 49KB ->
// 3 blocks/CU = 12 waves/CU (was 8). Layer1 widened to 64 h-cols/wave
// (acc1[2][4]): a-frag reuse x2 -> halved LDS read per FLOP. Known cost:
// W1 L2 traffic 2.1->4.3 GB (each block reads full W1) — floor ~125us, below
// current 343us; revisit Mtile if next profile shows L2-bound.
//
// MFMA layouts (m89/m120-verified):
//   A: A[m][k], m=lane&15, k=(lane>>4)*8+j (j=0..7)
//   B: B[k][n], n=lane&15, k=(lane>>4)*8+j
//   C/D: col=lane&15, row=(lane>>4)*4+reg

typedef __attribute__((ext_vector_type(8))) short short8x;
typedef __attribute__((ext_vector_type(4))) float float4x;

#define C_DIM 101

__device__ __forceinline__ unsigned short f2bf(float f) {
  unsigned int u = __builtin_bit_cast(unsigned int, f);
  u += 0x7fffu + ((u >> 16) & 1u);     // round-to-nearest-even
  return (unsigned short)(u >> 16);
}

// ---- W1 (+Wg) -> bf16, B-frag packed: frag = ntile*16+kf ; elem = frag*512 + lane*8 + j
__global__ void conv_w1(const float* __restrict__ W1, const float* __restrict__ Wg,
                        unsigned short* __restrict__ out) {
  int s = blockIdx.x * blockDim.x + threadIdx.x;   // slot = frag*64 + lane
  int l = s & 63;
  int frag = s >> 6;
  int kf = frag & 15;
  int ntile = frag >> 4;
  int n = (ntile << 4) | (l & 15);
  int k = (kf << 5) | ((l >> 4) << 3);
  short8x v;
#pragma unroll
  for (int j = 0; j < 8; ++j) {
    int kk = k + j;
    float f;
    if (n < 2048)      f = W1[((size_t)(n >> 8) * 512 + kk) * 256 + (n & 255)];
    else if (n < 2056) f = Wg[(size_t)kk * 8 + (n - 2048)];
    else               f = 0.f;
    v[j] = (short)f2bf(f);
  }
  *(short8x*)(out + (size_t)s * 8) = v;
}

// ---- W2 -> bf16, B-frag packed: frag = ntile*64+kf ; ntile 0..7, kf 0..63 (K=2048)
__global__ void conv_w2(const float* __restrict__ W2, unsigned short* __restrict__ out) {
  int s = blockIdx.x * blockDim.x + threadIdx.x;
  int l = s & 63;
  int frag = s >> 6;
  int kf = frag & 63;
  int ntile = frag >> 6;
  int c = (ntile << 4) | (l & 15);
  int k = (kf << 5) | ((l >> 4) << 3);
  short8x v;
#pragma unroll
  for (int j = 0; j < 8; ++j) {
    int kk = k + j;                       // e = kk>>8, h = kk&255
    float f = (c < C_DIM) ? W2[((size_t)(kk >> 8) * 256 + (kk & 255)) * C_DIM + c] : 0.f;
    v[j] = (short)f2bf(f);
  }
  *(short8x*)(out + (size_t)s * 8) = v;
}

// ---- fused main kernel: 32 rows/block, 256 threads (4 waves), 3 blocks/CU
__global__ __launch_bounds__(256, 3) void moe_main(
    const float* __restrict__ x, const float* __restrict__ b1,
    const float* __restrict__ b2, const float* __restrict__ bg,
    const unsigned short* __restrict__ W1bf, const unsigned short* __restrict__ W2bf,
    float* __restrict__ out) {
  __shared__ unsigned short xA[32 * 512];   // 32 KB: x A-frags [mt*16+kf][lane*8+j]
  __shared__ unsigned short hA[16 * 512];   // 16 KB: h' A-frags [kf2*2+mt][lane*8+j]
  __shared__ float gt[8 * 32];              //  1 KB: gates^T [e][row]
  float* graw = (float*)hA;                 // raw gate logits [32][8]; pre-loop only

  const int tid = threadIdx.x;
  const int w = tid >> 6;     // wave 0..3
  const int l = tid & 63;     // lane
  const int quad = l >> 4;
  const int p = l & 15;
  const int r0 = blockIdx.x * 32;

  // ---- stage x -> bf16 A-frag LDS (coalesced float4 x2 reads, b128 LDS writes)
#pragma unroll
  for (int it = 0; it < 8; ++it) {
    int g = tid + it * 256;            // m = g>>6 (0..31), k0 = (g&63)*8
    int m = g >> 6;
    int k0 = (g & 63) << 3;
    const float* src = x + (size_t)(r0 + m) * 512 + k0;
    float4 f0 = *(const float4*)src;
    float4 f1 = *(const float4*)(src + 4);
    short8x v;
    v[0] = (short)f2bf(f0.x); v[1] = (short)f2bf(f0.y);
    v[2] = (short)f2bf(f0.z); v[3] = (short)f2bf(f0.w);
    v[4] = (short)f2bf(f1.x); v[5] = (short)f2bf(f1.y);
    v[6] = (short)f2bf(f1.z); v[7] = (short)f2bf(f1.w);
    int mt = m >> 4;
    int kfrag = k0 >> 5;
    int lane = (((k0 >> 3) & 3) << 4) | (m & 15);
    *(short8x*)&xA[(size_t)(((mt << 4) | kfrag) * 64 + lane) * 8] = v;
  }
  __syncthreads();

  // ---- gate logits: waves 0,1 each do one 16-row tile x 16 gate cols (ntile 128)
  if (w < 2) {
    float4x acc = {0.f, 0.f, 0.f, 0.f};
#pragma unroll 2
    for (int kf = 0; kf < 16; ++kf) {
      short8x a = *(const short8x*)&xA[(size_t)((w * 16 + kf) * 64 + l) * 8];
      short8x b = *(const short8x*)(W1bf + ((size_t)(128 * 16 + kf) * 512 + l * 8));
      acc = __builtin_amdgcn_mfma_f32_16x16x32_bf16(a, b, acc, 0, 0, 0);
    }
    if (p < 8) {
      float bgv = bg[p];
#pragma unroll
      for (int r = 0; r < 4; ++r)
        graw[(w * 16 + quad * 4 + r) * 8 + p] = acc[r] + bgv;
    }
  }
  __syncthreads();
  // softmax over E=8 per row, fp32; write transposed gt[e][row]
  if (tid < 32) {
    float v[8], mx = -1e30f;
#pragma unroll
    for (int e = 0; e < 8; ++e) { v[e] = graw[tid * 8 + e]; mx = fmaxf(mx, v[e]); }
    float s = 0.f;
#pragma unroll
    for (int e = 0; e < 8; ++e) { v[e] = expf(v[e] - mx); s += v[e]; }
    float inv = 1.f / s;
#pragma unroll
    for (int e = 0; e < 8; ++e) gt[e * 32 + tid] = v[e] * inv;
  }
  __syncthreads();   // graw (hA alias) reads done before first hA write

  // ---- main loop over 8 experts (nt = e, 256 h-cols each)
  float4x zero = {0.f, 0.f, 0.f, 0.f};
  float4x acc2[2][2];                    // layer2: [mt][ct2], wave w owns ct = 2w+ct2
  acc2[0][0] = zero; acc2[0][1] = zero; acc2[1][0] = zero; acc2[1][1] = zero;
  const int ct0 = w * 2;
  const int ctmax = (w == 3) ? 1 : 2;    // ct=7 is all-padding (C=101)

  for (int nt = 0; nt < 8; ++nt) {
    // layer1: wave w covers h-cols [nt*256 + w*64, +64), all 32 rows
    float4x acc1[2][4];                  // [mt][nc]
#pragma unroll
    for (int mt = 0; mt < 2; ++mt)
#pragma unroll
      for (int nc = 0; nc < 4; ++nc) acc1[mt][nc] = zero;
#pragma unroll 2
    for (int kf = 0; kf < 16; ++kf) {
      short8x a0 = *(const short8x*)&xA[(size_t)((0 * 16 + kf) * 64 + l) * 8];
      short8x a1 = *(const short8x*)&xA[(size_t)((1 * 16 + kf) * 64 + l) * 8];
#pragma unroll
      for (int nc = 0; nc < 4; ++nc) {
        int ntile = nt * 16 + w * 4 + nc;
        short8x b = *(const short8x*)(W1bf + ((size_t)(ntile * 16 + kf) * 512 + l * 8));
        acc1[0][nc] = __builtin_amdgcn_mfma_f32_16x16x32_bf16(a0, b, acc1[0][nc], 0, 0, 0);
        acc1[1][nc] = __builtin_amdgcn_mfma_f32_16x16x32_bf16(a1, b, acc1[1][nc], 0, 0, 0);
      }
    }

    // gates for this expert (gt never overwritten; safe pre-barrier)
    float4x gv0 = *(const float4x*)&gt[nt * 32 + 0  + quad * 4];
    float4x gv1 = *(const float4x*)&gt[nt * 32 + 16 + quad * 4];

    __syncthreads();                     // prev nt's layer2 reads of hA complete

    // epilogue: +b1, relu, *gate(e==nt), bf16 -> shared hA (C->A transpose)
#pragma unroll
    for (int nc = 0; nc < 4; ++nc) {
      int cw = w * 64 + nc * 16 + p;     // col within nt-tile (0..255)
      float b1v = b1[nt * 256 + cw];
      int koff = cw & 31;
      int fbase = (cw >> 5) << 1;        // kf2*2
      int jj = koff & 7;
      int ldbase = (koff >> 3) << 4;     // chunk*16
#pragma unroll
      for (int mt = 0; mt < 2; ++mt) {
#pragma unroll
        for (int r = 0; r < 4; ++r) {
          float hv = fmaxf(acc1[mt][nc][r] + b1v, 0.f) * (mt ? gv1[r] : gv0[r]);
          hA[(fbase + mt) * 512 + (ldbase + quad * 4 + r) * 8 + jj] = f2bf(hv);
        }
      }
    }
    __syncthreads();                     // all h' published

    // layer2: wave w accumulates its 2 ct-tiles over this expert's full K=256
#pragma unroll 2
    for (int kf2 = 0; kf2 < 8; ++kf2) {
      short8x a0 = *(const short8x*)&hA[(size_t)(((kf2 << 1) | 0) * 64 + l) * 8];
      short8x a1 = *(const short8x*)&hA[(size_t)(((kf2 << 1) | 1) * 64 + l) * 8];
#pragma unroll
      for (int ct2 = 0; ct2 < 2; ++ct2) {
        if (ct2 < ctmax) {
          short8x b = *(const short8x*)(W2bf +
              ((size_t)((ct0 + ct2) * 64 + nt * 8 + kf2) * 512 + l * 8));
          acc2[0][ct2] = __builtin_amdgcn_mfma_f32_16x16x32_bf16(a0, b, acc2[0][ct2], 0, 0, 0);
          acc2[1][ct2] = __builtin_amdgcn_mfma_f32_16x16x32_bf16(a1, b, acc2[1][ct2], 0, 0, 0);
        }
      }
    }
  }

  // ---- epilogue: + gate-weighted b2, store (no cross-wave reduction needed)
#pragma unroll
  for (int mt = 0; mt < 2; ++mt) {
    float4x ge[8];
#pragma unroll
    for (int e = 0; e < 8; ++e)
      ge[e] = *(const float4x*)&gt[e * 32 + mt * 16 + quad * 4];
#pragma unroll
    for (int ct2 = 0; ct2 < 2; ++ct2) {
      int c = (ct0 + ct2) * 16 + p;
      if (c < C_DIM) {
        float4x bias = {0.f, 0.f, 0.f, 0.f};
#pragma unroll
        for (int e = 0; e < 8; ++e) {
          float b2v = b2[e * C_DIM + c];
          bias[0] += ge[e][0] * b2v; bias[1] += ge[e][1] * b2v;
          bias[2] += ge[e][2] * b2v; bias[3] += ge[e][3] * b2v;
        }
#pragma unroll
        for (int r = 0; r < 4; ++r)
          out[(size_t)(r0 + mt * 16 + quad * 4 + r) * C_DIM + c] = acc2[mt][ct2][r] + bias[r];
      }
    }
  }
}

extern "C" void kernel_launch(void* const* d_in, const int* in_sizes, int n_in,
                              void* d_out, int out_size, void* d_ws, size_t ws_size,
                              hipStream_t stream) {
  const float* x  = (const float*)d_in[0];
  const float* W1 = (const float*)d_in[1];
  const float* b1 = (const float*)d_in[2];
  const float* W2 = (const float*)d_in[3];
  const float* b2 = (const float*)d_in[4];
  const float* Wg = (const float*)d_in[5];
  const float* bg = (const float*)d_in[6];
  float* out = (float*)d_out;

  unsigned short* W1bf = (unsigned short*)d_ws;
  unsigned short* W2bf = (unsigned short*)((char*)d_ws + (size_t)129 * 16 * 512 * 2);

  conv_w1<<<516, 256, 0, stream>>>(W1, Wg, W1bf);   // 129*16*64 slots
  conv_w2<<<128, 256, 0, stream>>>(W2, W2bf);       // 8*64*64 slots
  moe_main<<<2048, 256, 0, stream>>>(x, b1, b2, bg, W1bf, W2bf, out);
}